// Round 4
// baseline (9073.614 us; speedup 1.0000x reference)
//
#include <hip/hip_runtime.h>
#include <hip/hip_bf16.h>
#include <stdint.h>

// ---------------------------------------------------------------------------
// SwiGLU + int8 weight-quant emulation (VNNILinear), MI355X gfx950. Round 4:
//   Fused GEMM1/3: mfma_i32_32x32x32_i8, BK=32, 4-slot 64 KB LDS ring
//     -> 2 blocks/CU; stage 3 tiles ahead, vmcnt(4) gate. Linear LDS (32B
//     rows are bank-uniform for 32x32 frag reads).
//   GEMM2: mfma_f32_32x32x16_bf16, 256x256 tile, BK=32, 4-slot 128 KB ring,
//     chunk-XOR swizzle (c ^= r&3) on 64B rows, both-sides.
// ---------------------------------------------------------------------------

typedef short bf16x8 __attribute__((ext_vector_type(8)));
typedef float f32x4  __attribute__((ext_vector_type(4)));
typedef float f32x16 __attribute__((ext_vector_type(16)));
typedef int   i32x4  __attribute__((ext_vector_type(4)));
typedef int   i32x16 __attribute__((ext_vector_type(16)));

__device__ __forceinline__ unsigned short f2bf(float f) {
  unsigned u = __builtin_bit_cast(unsigned, f);
  u += 0x7FFFu + ((u >> 16) & 1u);   // RNE
  return (unsigned short)(u >> 16);
}

#define GLOAD_LDS16(gaddr, laddr)                                             \
  __builtin_amdgcn_global_load_lds(                                           \
      (const __attribute__((address_space(1))) void*)(gaddr),                 \
      (__attribute__((address_space(3))) void*)(laddr), 16, 0, 0)

#define FENCE()      asm volatile("" ::: "memory")
#define BAR()        __builtin_amdgcn_s_barrier()
#define WAIT_LGKM0() asm volatile("s_waitcnt lgkmcnt(0)" ::: "memory")
#define WAIT_VM8()   asm volatile("s_waitcnt vmcnt(8)" ::: "memory")
#define WAIT_VM4()   asm volatile("s_waitcnt vmcnt(4)" ::: "memory")
#define WAIT_VM2()   asm volatile("s_waitcnt vmcnt(2)" ::: "memory")
#define WAIT_VM0()   asm volatile("s_waitcnt vmcnt(0)" ::: "memory")
#define SFENCE()     __builtin_amdgcn_sched_barrier(0)

// --------------------------- preprocessing --------------------------------

__global__ void quant_rows_i8_kernel(const float* __restrict__ w,
                                     char* __restrict__ q,
                                     float* __restrict__ scale, int cols,
                                     float clip) {
  const int row = blockIdx.x;
  const float* wr = w + (size_t)row * cols;
  char* qr = q + (size_t)row * cols;

  float m = 0.f;
  for (int c = threadIdx.x * 4; c < cols; c += blockDim.x * 4) {
    float4 v = *reinterpret_cast<const float4*>(wr + c);
    m = fmaxf(m, fmaxf(fmaxf(fabsf(v.x), fabsf(v.y)),
                       fmaxf(fabsf(v.z), fabsf(v.w))));
  }
#pragma unroll
  for (int off = 32; off; off >>= 1) m = fmaxf(m, __shfl_xor(m, off));
  __shared__ float smax[4];
  if ((threadIdx.x & 63) == 0) smax[threadIdx.x >> 6] = m;
  __syncthreads();
  m = fmaxf(fmaxf(smax[0], smax[1]), fmaxf(smax[2], smax[3]));

  const float s = fmaxf(m, clip) / 127.0f;
  if (threadIdx.x == 0) scale[row] = s;
  for (int c = threadIdx.x * 4; c < cols; c += blockDim.x * 4) {
    float4 v = *reinterpret_cast<const float4*>(wr + c);
    int b0 = (int)rintf(v.x / s), b1 = (int)rintf(v.y / s);
    int b2 = (int)rintf(v.z / s), b3 = (int)rintf(v.w / s);
    unsigned pk = (b0 & 0xff) | ((b1 & 0xff) << 8) | ((b2 & 0xff) << 16)
                  | ((b3 & 0xff) << 24);
    *reinterpret_cast<unsigned*>(qr + c) = pk;
  }
}

__global__ void quant_rows_bf16_kernel(const float* __restrict__ w,
                                       unsigned short* __restrict__ wq,
                                       int cols) {
  const int row = blockIdx.x;
  const float* wr = w + (size_t)row * cols;
  unsigned short* wqr = wq + (size_t)row * cols;

  float m = 0.f;
  for (int c = threadIdx.x * 4; c < cols; c += blockDim.x * 4) {
    float4 v = *reinterpret_cast<const float4*>(wr + c);
    m = fmaxf(m, fmaxf(fmaxf(fabsf(v.x), fabsf(v.y)),
                       fmaxf(fabsf(v.z), fabsf(v.w))));
  }
#pragma unroll
  for (int off = 32; off; off >>= 1) m = fmaxf(m, __shfl_xor(m, off));
  __shared__ float smax[4];
  if ((threadIdx.x & 63) == 0) smax[threadIdx.x >> 6] = m;
  __syncthreads();
  m = fmaxf(fmaxf(smax[0], smax[1]), fmaxf(smax[2], smax[3]));

  const float s = fmaxf(m, 1e-6f) / 127.0f;
  for (int c = threadIdx.x * 4; c < cols; c += blockDim.x * 4) {
    float4 v = *reinterpret_cast<const float4*>(wr + c);
    ushort4 o;
    o.x = f2bf(rintf(v.x / s) * s);
    o.y = f2bf(rintf(v.y / s) * s);
    o.z = f2bf(rintf(v.z / s) * s);
    o.w = f2bf(rintf(v.w / s) * s);
    *reinterpret_cast<ushort4*>(wqr + c) = o;
  }
}

// ------------------------------ GEMMs -------------------------------------

__device__ __forceinline__ void xcd_swizzle(int& bx, int& by, int gx, int gy) {
  int nwg = gx * gy;              // both grids are % 8 == 0
  int bid = by * gx + bx;
  int cpx = nwg >> 3;
  int s = (bid & 7) * cpx + (bid >> 3);
  by = s / gx;
  bx = s % gx;
}

// Fused int8 GEMM: H = silu((xq@w1q^T)*sx*sw1) * ((xq@w3q^T)*sx*sw3), bf16.
// Tile 256x128, BK=32, 8 waves (2M x 4N), per-wave 128 rows x 32 dual-cols.
// mfma_i32_32x32x32_i8: A row=lane&31, k=(lane>>5)*16+i; C col=lane&31,
// row=(reg&3)+8*(reg>>2)+4*(lane>>5).
__global__ __launch_bounds__(512, 4)
void gemm_i8_swiglu_kernel(const char* __restrict__ Aq,
                           const char* __restrict__ B1q,
                           const char* __restrict__ B3q,
                           const float* __restrict__ sx,
                           const float* __restrict__ sw1,
                           const float* __restrict__ sw3,
                           unsigned short* __restrict__ H,
                           int M, int N, int K) {
  // 4 slots x 16 KB: A 256x32B [0,8K), B1 128x32B [8K,12K), B3 [12K,16K)
  __shared__ alignas(1024) char lds[65536];

  int bx = blockIdx.x, by = blockIdx.y;
  xcd_swizzle(bx, by, gridDim.x, gridDim.y);
  const int brow = by * 256, bcol = bx * 128;

  const int t = threadIdx.x, lane = t & 63, w = t >> 6;
  const int wr = w >> 2, wc = w & 3;
  const int l31 = lane & 31, hi = lane >> 5;
  const int NT = K >> 5;   // BK=32

  // staging (linear): A covers 256 rows x 2 chunks; B: waves 0-3 -> B1,
  // waves 4-7 -> B3 (dest t*16 lands in the right region automatically).
  const char* srcA = Aq + (size_t)(brow + (t >> 1)) * K + (t & 1) * 16;
  const char* srcB = (t < 256 ? B1q : B3q)
                   + (size_t)(bcol + ((t & 255) >> 1)) * K + (t & 1) * 16;

#define STAGE(kt)                                                             \
  {                                                                           \
    const int s2 = ((kt) & 3) * 16384;                                        \
    const size_t ko = (size_t)(kt) * 32;                                      \
    GLOAD_LDS16(srcA + ko, lds + s2 + t * 16);                                \
    GLOAD_LDS16(srcB + ko, lds + s2 + 8192 + t * 16);                         \
  }

  // prologue: 3 tiles in flight (6 loads); drain to 4 -> tile 0 landed
  STAGE(0); STAGE(1); STAGE(2);
  WAIT_VM4();
  FENCE(); BAR();

  i32x16 acc[4][2] = {};     // [m-tile][B1|B3]
  const int aoff = (wr * 128 + l31) * 32 + hi * 16;
  const int boff1 = 8192 + (wc * 32 + l31) * 32 + hi * 16;
  const int boff3 = boff1 + 4096;

  for (int k = 0; k < NT; ++k) {
    const char* sl = lds + (k & 3) * 16384;
    i32x4 afr[4], b1f, b3f;
#pragma unroll
    for (int m = 0; m < 4; ++m)
      afr[m] = *reinterpret_cast<const i32x4*>(sl + aoff + m * 1024);
    b1f = *reinterpret_cast<const i32x4*>(sl + boff1);
    b3f = *reinterpret_cast<const i32x4*>(sl + boff3);
    if (k + 3 < NT) {
      STAGE(k + 3);
      WAIT_VM4();     // tile k+1 landed; k+2,k+3 in flight
    } else if (k == NT - 3) {
      WAIT_VM2();
    } else {
      WAIT_VM0();
    }
    FENCE(); BAR();
    WAIT_LGKM0(); SFENCE();
    __builtin_amdgcn_s_setprio(1);
#pragma unroll
    for (int m = 0; m < 4; ++m) {
      acc[m][0] = __builtin_amdgcn_mfma_i32_32x32x32_i8(afr[m], b1f,
                                                        acc[m][0], 0, 0, 0);
      acc[m][1] = __builtin_amdgcn_mfma_i32_32x32x32_i8(afr[m], b3f,
                                                        acc[m][1], 0, 0, 0);
    }
    __builtin_amdgcn_s_setprio(0);
    FENCE(); BAR();
  }
#undef STAGE

  // ---- epilogue: dequant + SwiGLU -> bf16 ----
  const int ocol = bcol + wc * 32 + l31;
  const int rowb = brow + wr * 128 + 4 * hi;
  const float sw1c = sw1[ocol], sw3c = sw3[ocol];
#pragma unroll
  for (int m = 0; m < 4; ++m) {
#pragma unroll
    for (int rq = 0; rq < 4; ++rq) {
      const int r0 = rowb + m * 32 + 8 * rq;
      const f32x4 sx4 = *reinterpret_cast<const f32x4*>(sx + r0);
#pragma unroll
      for (int j = 0; j < 4; ++j) {
        float y1 = (float)acc[m][0][rq * 4 + j] * (sx4[j] * sw1c);
        float y3 = (float)acc[m][1][rq * 4 + j] * (sx4[j] * sw3c);
        float hv = (y1 / (1.f + __expf(-y1))) * y3;
        H[(size_t)(r0 + j) * N + ocol] = f2bf(hv);
      }
    }
  }
}

// bf16 GEMM: C = A @ B^T (fp32 out). Tile 256x256, BK=32, 32x32x16 MFMA.
// 64B rows -> chunk swizzle c' = c ^ (r&3), both-sides.
__global__ __launch_bounds__(512, 2)
void gemm_bf16_kernel(const unsigned short* __restrict__ A,
                      const unsigned short* __restrict__ B,
                      float* __restrict__ C, int M, int N, int K) {
  // 4 slots x 16384 sh (32 KB): A 256x32sh [0,8192), B 256x32sh [8192,16384)
  __shared__ alignas(1024) unsigned short lds[65536];

  int bx = blockIdx.x, by = blockIdx.y;
  xcd_swizzle(bx, by, gridDim.x, gridDim.y);
  const int brow = by * 256, bcol = bx * 256;

  const int t = threadIdx.x, lane = t & 63, w = t >> 6;
  const int wr = w >> 2, wc = w & 3;
  const int l31 = lane & 31, hi = lane >> 5, rx3 = lane & 3;
  const int NT = K >> 5;

  // staging with pre-swizzled source chunk: dest chunk c'=t&3, src c=c'^(r&3)
  const int rS = t >> 2;
  const int cS = ((t & 3) ^ ((t >> 2) & 3)) * 8;
  const unsigned short* srcA = A + (size_t)(brow + rS) * K + cS;
  const unsigned short* srcB = B + (size_t)(bcol + rS) * K + cS;

#define STAGE_A(kt)                                                           \
  {                                                                           \
    const int s2 = ((kt) & 3) * 16384;                                        \
    const size_t ko = (size_t)(kt) * 32;                                      \
    GLOAD_LDS16(srcA + ko, &lds[s2 + t * 8]);                                 \
    GLOAD_LDS16(srcA + (size_t)128 * K + ko, &lds[s2 + 4096 + t * 8]);        \
  }
#define STAGE_B(kt)                                                           \
  {                                                                           \
    const int s2 = ((kt) & 3) * 16384;                                        \
    const size_t ko = (size_t)(kt) * 32;                                      \
    GLOAD_LDS16(srcB + ko, &lds[s2 + 8192 + t * 8]);                          \
    GLOAD_LDS16(srcB + (size_t)128 * K + ko, &lds[s2 + 12288 + t * 8]);       \
  }

  STAGE_A(0); STAGE_B(0);
  STAGE_A(1); STAGE_B(1);
  STAGE_A(2); STAGE_B(2);
  WAIT_VM8();
  FENCE(); BAR();

  f32x16 acc[4][2] = {};
  // fragment sh-indices (slot-relative), swizzled: r*32 + ((c ^ (r&3))*8),
  // c = 2*kh + hi.  r&3 == lane&3 for all our rows.
  int aIdx[4][2], bIdx[2][2];
#pragma unroll
  for (int m = 0; m < 4; ++m)
#pragma unroll
    for (int kh = 0; kh < 2; ++kh)
      aIdx[m][kh] = (wr * 128 + l31 + m * 32) * 32
                    + (((2 * kh + hi) ^ rx3) * 8);
#pragma unroll
  for (int n = 0; n < 2; ++n)
#pragma unroll
    for (int kh = 0; kh < 2; ++kh)
      bIdx[n][kh] = 8192 + (wc * 64 + l31 + n * 32) * 32
                    + (((2 * kh + hi) ^ rx3) * 8);

  for (int k = 0; k < NT; ++k) {
    const unsigned short* sl = &lds[(k & 3) * 16384];
    const bool pf = (k + 3 < NT);
    bf16x8 afr[2][2], bfr[2][2];

    // ---- phase A: m-tiles 0,1 ----
#pragma unroll
    for (int m = 0; m < 2; ++m)
#pragma unroll
      for (int kh = 0; kh < 2; ++kh)
        afr[m][kh] = *reinterpret_cast<const bf16x8*>(sl + aIdx[m][kh]);
#pragma unroll
    for (int n = 0; n < 2; ++n)
#pragma unroll
      for (int kh = 0; kh < 2; ++kh)
        bfr[n][kh] = *reinterpret_cast<const bf16x8*>(sl + bIdx[n][kh]);
    if (pf) STAGE_A(k + 3);
    FENCE(); BAR();
    WAIT_LGKM0(); SFENCE();
    __builtin_amdgcn_s_setprio(1);
#pragma unroll
    for (int m = 0; m < 2; ++m)
#pragma unroll
      for (int n = 0; n < 2; ++n)
#pragma unroll
        for (int kh = 0; kh < 2; ++kh)
          acc[m][n] = __builtin_amdgcn_mfma_f32_32x32x16_bf16(
              afr[m][kh], bfr[n][kh], acc[m][n], 0, 0, 0);
    __builtin_amdgcn_s_setprio(0);
    FENCE(); BAR();

    // ---- phase B: m-tiles 2,3 (B frags reused) ----
#pragma unroll
    for (int m = 0; m < 2; ++m)
#pragma unroll
      for (int kh = 0; kh < 2; ++kh)
        afr[m][kh] = *reinterpret_cast<const bf16x8*>(sl + aIdx[m + 2][kh]);
    if (pf) {
      STAGE_B(k + 3);
      WAIT_VM8();
    } else if (k == NT - 3) {
      WAIT_VM4();
    } else {
      WAIT_VM0();
    }
    FENCE(); BAR();
    WAIT_LGKM0(); SFENCE();
    __builtin_amdgcn_s_setprio(1);
#pragma unroll
    for (int m = 0; m < 2; ++m)
#pragma unroll
      for (int n = 0; n < 2; ++n)
#pragma unroll
        for (int kh = 0; kh < 2; ++kh)
          acc[m + 2][n] = __builtin_amdgcn_mfma_f32_32x32x16_bf16(
              afr[m][kh], bfr[n][kh], acc[m + 2][n], 0, 0, 0);
    __builtin_amdgcn_s_setprio(0);
    FENCE(); BAR();
  }
#undef STAGE_A
#undef STAGE_B

  const int ocol = bcol + wc * 64 + l31;
  const int rowb = brow + wr * 128 + 4 * hi;
#pragma unroll
  for (int m = 0; m < 4; ++m)
#pragma unroll
    for (int n = 0; n < 2; ++n)
#pragma unroll
      for (int rq = 0; rq < 4; ++rq)
#pragma unroll
        for (int j = 0; j < 4; ++j)
          C[(size_t)(rowb + m * 32 + 8 * rq + j) * N + (ocol + n * 32)] =
              acc[m][n][rq * 4 + j];
}

// ------------------------------ launch -------------------------------------

extern "C" void kernel_launch(void* const* d_in, const int* in_sizes, int n_in,
                              void* d_out, int out_size, void* d_ws,
                              size_t ws_size, hipStream_t stream) {
  const float* x  = (const float*)d_in[0];
  const float* w1 = (const float*)d_in[1];
  const float* w2 = (const float*)d_in[2];
  const float* w3 = (const float*)d_in[3];
  float* out = (float*)d_out;

  const int DIM = 4096, HID = 8192;
  const int M = in_sizes[0] / DIM;  // 8192

  char* xq  = (char*)d_ws;                              // M*DIM    (32 MB)
  char* w1q = xq + (size_t)M * DIM;                     // HID*DIM  (32 MB)
  char* w3q = w1q + (size_t)HID * DIM;                  // HID*DIM  (32 MB)
  unsigned short* w2b = (unsigned short*)(w3q + (size_t)HID * DIM);  // 64 MB
  unsigned short* h = w2b + (size_t)DIM * HID;          // M*HID bf16 (128 MB)
  float* sx  = (float*)(h + (size_t)M * HID);           // M
  float* sw1 = sx + M;                                  // HID
  float* sw3 = sw1 + HID;                               // HID

  quant_rows_i8_kernel<<<HID, 256, 0, stream>>>(w1, w1q, sw1, DIM, 1e-6f);
  quant_rows_i8_kernel<<<HID, 256, 0, stream>>>(w3, w3q, sw3, DIM, 1e-6f);
  quant_rows_i8_kernel<<<M, 256, 0, stream>>>(x, xq, sx, DIM, 1e-30f);
  quant_rows_bf16_kernel<<<DIM, 256, 0, stream>>>(w2, w2b, HID);

  gemm_i8_swiglu_kernel<<<dim3(HID / 128, M / 256), 512, 0, stream>>>(
      xq, w1q, w3q, sx, sw1, sw3, h, M, HID, DIM);
  gemm_bf16_kernel<<<dim3(DIM / 256, M / 256), 512, 0, stream>>>(
      h, w2b, out, M, DIM, HID);
}

// Round 5
// 1513.471 us; speedup vs baseline: 5.9952x; 5.9952x over previous
//
#include <hip/hip_runtime.h>
#include <hip/hip_bf16.h>
#include <stdint.h>

// ---------------------------------------------------------------------------
// SwiGLU + int8 weight-quant emulation (VNNILinear), MI355X gfx950. Round 5:
//   Fused GEMM1/3: mfma_i32_32x32x32_i8, BK=32, 4-slot 64 KB LDS ring,
//     launch_bounds(512,2)  [R4 lesson: (512,4) halves the VGPR budget and
//     spills the 128-reg accumulator -> 42 GB scratch traffic, 14x slower].
//     i8 chunk swizzle c^=(r>>2)&1 both-sides: 4-way ds_read conflict -> 2-way.
//   GEMM2: mfma_f32_32x32x16_bf16, 256x256 tile, BK=32, c^=r&3 swizzle.
// ---------------------------------------------------------------------------

typedef short bf16x8 __attribute__((ext_vector_type(8)));
typedef float f32x4  __attribute__((ext_vector_type(4)));
typedef float f32x16 __attribute__((ext_vector_type(16)));
typedef int   i32x4  __attribute__((ext_vector_type(4)));
typedef int   i32x16 __attribute__((ext_vector_type(16)));

__device__ __forceinline__ unsigned short f2bf(float f) {
  unsigned u = __builtin_bit_cast(unsigned, f);
  u += 0x7FFFu + ((u >> 16) & 1u);   // RNE
  return (unsigned short)(u >> 16);
}

#define GLOAD_LDS16(gaddr, laddr)                                             \
  __builtin_amdgcn_global_load_lds(                                           \
      (const __attribute__((address_space(1))) void*)(gaddr),                 \
      (__attribute__((address_space(3))) void*)(laddr), 16, 0, 0)

#define FENCE()      asm volatile("" ::: "memory")
#define BAR()        __builtin_amdgcn_s_barrier()
#define WAIT_LGKM0() asm volatile("s_waitcnt lgkmcnt(0)" ::: "memory")
#define WAIT_VM8()   asm volatile("s_waitcnt vmcnt(8)" ::: "memory")
#define WAIT_VM4()   asm volatile("s_waitcnt vmcnt(4)" ::: "memory")
#define WAIT_VM2()   asm volatile("s_waitcnt vmcnt(2)" ::: "memory")
#define WAIT_VM0()   asm volatile("s_waitcnt vmcnt(0)" ::: "memory")
#define SFENCE()     __builtin_amdgcn_sched_barrier(0)

// --------------------------- preprocessing --------------------------------

__global__ void quant_rows_i8_kernel(const float* __restrict__ w,
                                     char* __restrict__ q,
                                     float* __restrict__ scale, int cols,
                                     float clip) {
  const int row = blockIdx.x;
  const float* wr = w + (size_t)row * cols;
  char* qr = q + (size_t)row * cols;

  float m = 0.f;
  for (int c = threadIdx.x * 4; c < cols; c += blockDim.x * 4) {
    float4 v = *reinterpret_cast<const float4*>(wr + c);
    m = fmaxf(m, fmaxf(fmaxf(fabsf(v.x), fabsf(v.y)),
                       fmaxf(fabsf(v.z), fabsf(v.w))));
  }
#pragma unroll
  for (int off = 32; off; off >>= 1) m = fmaxf(m, __shfl_xor(m, off));
  __shared__ float smax[4];
  if ((threadIdx.x & 63) == 0) smax[threadIdx.x >> 6] = m;
  __syncthreads();
  m = fmaxf(fmaxf(smax[0], smax[1]), fmaxf(smax[2], smax[3]));

  const float s = fmaxf(m, clip) / 127.0f;
  if (threadIdx.x == 0) scale[row] = s;
  for (int c = threadIdx.x * 4; c < cols; c += blockDim.x * 4) {
    float4 v = *reinterpret_cast<const float4*>(wr + c);
    int b0 = (int)rintf(v.x / s), b1 = (int)rintf(v.y / s);
    int b2 = (int)rintf(v.z / s), b3 = (int)rintf(v.w / s);
    unsigned pk = (b0 & 0xff) | ((b1 & 0xff) << 8) | ((b2 & 0xff) << 16)
                  | ((b3 & 0xff) << 24);
    *reinterpret_cast<unsigned*>(qr + c) = pk;
  }
}

__global__ void quant_rows_bf16_kernel(const float* __restrict__ w,
                                       unsigned short* __restrict__ wq,
                                       int cols) {
  const int row = blockIdx.x;
  const float* wr = w + (size_t)row * cols;
  unsigned short* wqr = wq + (size_t)row * cols;

  float m = 0.f;
  for (int c = threadIdx.x * 4; c < cols; c += blockDim.x * 4) {
    float4 v = *reinterpret_cast<const float4*>(wr + c);
    m = fmaxf(m, fmaxf(fmaxf(fabsf(v.x), fabsf(v.y)),
                       fmaxf(fabsf(v.z), fabsf(v.w))));
  }
#pragma unroll
  for (int off = 32; off; off >>= 1) m = fmaxf(m, __shfl_xor(m, off));
  __shared__ float smax[4];
  if ((threadIdx.x & 63) == 0) smax[threadIdx.x >> 6] = m;
  __syncthreads();
  m = fmaxf(fmaxf(smax[0], smax[1]), fmaxf(smax[2], smax[3]));

  const float s = fmaxf(m, 1e-6f) / 127.0f;
  for (int c = threadIdx.x * 4; c < cols; c += blockDim.x * 4) {
    float4 v = *reinterpret_cast<const float4*>(wr + c);
    ushort4 o;
    o.x = f2bf(rintf(v.x / s) * s);
    o.y = f2bf(rintf(v.y / s) * s);
    o.z = f2bf(rintf(v.z / s) * s);
    o.w = f2bf(rintf(v.w / s) * s);
    *reinterpret_cast<ushort4*>(wqr + c) = o;
  }
}

// ------------------------------ GEMMs -------------------------------------

__device__ __forceinline__ void xcd_swizzle(int& bx, int& by, int gx, int gy) {
  int nwg = gx * gy;              // both grids are % 8 == 0
  int bid = by * gx + bx;
  int cpx = nwg >> 3;
  int s = (bid & 7) * cpx + (bid >> 3);
  by = s / gx;
  bx = s % gx;
}

// Fused int8 GEMM: H = silu((xq@w1q^T)*sx*sw1) * ((xq@w3q^T)*sx*sw3), bf16.
// Tile 256x128, BK=32, 8 waves (2M x 4N), per-wave 128 rows x 32 dual-cols.
// mfma_i32_32x32x32_i8: A row=lane&31, k=(lane>>5)*16+i; C col=lane&31,
// row=(reg&3)+8*(reg>>2)+4*(lane>>5).
// i8 LDS rows are 32 B (2 chunks of 16 B); stored chunk = c ^ ((row>>2)&1)
// (both-sides involution) -> ds_read_b128 conflicts drop 4-way -> 2-way(free).
__global__ __launch_bounds__(512, 2)
void gemm_i8_swiglu_kernel(const char* __restrict__ Aq,
                           const char* __restrict__ B1q,
                           const char* __restrict__ B3q,
                           const float* __restrict__ sx,
                           const float* __restrict__ sw1,
                           const float* __restrict__ sw3,
                           unsigned short* __restrict__ H,
                           int M, int N, int K) {
  // 4 slots x 16 KB: A 256x32B [0,8K), B1 128x32B [8K,12K), B3 [12K,16K)
  __shared__ alignas(1024) char lds[65536];

  int bx = blockIdx.x, by = blockIdx.y;
  xcd_swizzle(bx, by, gridDim.x, gridDim.y);
  const int brow = by * 256, bcol = bx * 128;

  const int t = threadIdx.x, lane = t & 63, w = t >> 6;
  const int wr = w >> 2, wc = w & 3;
  const int l31 = lane & 31, hi = lane >> 5;
  const int NT = K >> 5;   // BK=32

  // staging: thread t -> row t>>1, dest chunk t&1 (linear dest t*16);
  // source chunk = (t&1) ^ bit2(row) = (t&1) ^ ((t>>3)&1).
  const int gc16 = (((t & 1) ^ ((t >> 3) & 1))) * 16;
  const char* srcA = Aq + (size_t)(brow + (t >> 1)) * K + gc16;
  const char* srcB = (t < 256 ? B1q : B3q)
                   + (size_t)(bcol + ((t & 255) >> 1)) * K + gc16;

#define STAGE(kt)                                                             \
  {                                                                           \
    const int s2 = ((kt) & 3) * 16384;                                        \
    const size_t ko = (size_t)(kt) * 32;                                      \
    GLOAD_LDS16(srcA + ko, lds + s2 + t * 16);                                \
    GLOAD_LDS16(srcB + ko, lds + s2 + 8192 + t * 16);                         \
  }

  // prologue: 3 tiles in flight (6 loads); drain to 4 -> tile 0 landed
  STAGE(0); STAGE(1); STAGE(2);
  WAIT_VM4();
  FENCE(); BAR();

  i32x16 acc[4][2] = {};     // [m-tile][B1|B3]
  // read offsets with matching chunk swizzle: chunk = hi ^ bit2(row)
  const int aoff = (wr * 128 + l31) * 32 + ((hi ^ ((l31 >> 2) & 1)) * 16);
  const int boff1 = 8192 + (wc * 32 + l31) * 32
                    + ((hi ^ ((l31 >> 2) & 1)) * 16);
  const int boff3 = boff1 + 4096;

  for (int k = 0; k < NT; ++k) {
    const char* sl = lds + (k & 3) * 16384;
    i32x4 afr[4], b1f, b3f;
#pragma unroll
    for (int m = 0; m < 4; ++m)
      afr[m] = *reinterpret_cast<const i32x4*>(sl + aoff + m * 1024);
    b1f = *reinterpret_cast<const i32x4*>(sl + boff1);
    b3f = *reinterpret_cast<const i32x4*>(sl + boff3);
    if (k + 3 < NT) {
      STAGE(k + 3);
      WAIT_VM4();     // tile k+1 landed; k+2,k+3 in flight
    } else if (k == NT - 3) {
      WAIT_VM2();
    } else {
      WAIT_VM0();
    }
    FENCE(); BAR();
    WAIT_LGKM0(); SFENCE();
    __builtin_amdgcn_s_setprio(1);
#pragma unroll
    for (int m = 0; m < 4; ++m) {
      acc[m][0] = __builtin_amdgcn_mfma_i32_32x32x32_i8(afr[m], b1f,
                                                        acc[m][0], 0, 0, 0);
      acc[m][1] = __builtin_amdgcn_mfma_i32_32x32x32_i8(afr[m], b3f,
                                                        acc[m][1], 0, 0, 0);
    }
    __builtin_amdgcn_s_setprio(0);
    FENCE(); BAR();
  }
#undef STAGE

  // ---- epilogue: dequant + SwiGLU -> bf16 ----
  const int ocol = bcol + wc * 32 + l31;
  const int rowb = brow + wr * 128 + 4 * hi;
  const float sw1c = sw1[ocol], sw3c = sw3[ocol];
#pragma unroll
  for (int m = 0; m < 4; ++m) {
#pragma unroll
    for (int rq = 0; rq < 4; ++rq) {
      const int r0 = rowb + m * 32 + 8 * rq;
      const f32x4 sx4 = *reinterpret_cast<const f32x4*>(sx + r0);
#pragma unroll
      for (int j = 0; j < 4; ++j) {
        float y1 = (float)acc[m][0][rq * 4 + j] * (sx4[j] * sw1c);
        float y3 = (float)acc[m][1][rq * 4 + j] * (sx4[j] * sw3c);
        float hv = (y1 / (1.f + __expf(-y1))) * y3;
        H[(size_t)(r0 + j) * N + ocol] = f2bf(hv);
      }
    }
  }
}

// bf16 GEMM: C = A @ B^T (fp32 out). Tile 256x256, BK=32, 32x32x16 MFMA.
// 64B rows -> chunk swizzle c' = c ^ (r&3), both-sides.
__global__ __launch_bounds__(512, 2)
void gemm_bf16_kernel(const unsigned short* __restrict__ A,
                      const unsigned short* __restrict__ B,
                      float* __restrict__ C, int M, int N, int K) {
  // 4 slots x 16384 sh (32 KB): A 256x32sh [0,8192), B 256x32sh [8192,16384)
  __shared__ alignas(1024) unsigned short lds[65536];

  int bx = blockIdx.x, by = blockIdx.y;
  xcd_swizzle(bx, by, gridDim.x, gridDim.y);
  const int brow = by * 256, bcol = bx * 256;

  const int t = threadIdx.x, lane = t & 63, w = t >> 6;
  const int wr = w >> 2, wc = w & 3;
  const int l31 = lane & 31, hi = lane >> 5, rx3 = lane & 3;
  const int NT = K >> 5;

  // staging with pre-swizzled source chunk: dest chunk c'=t&3, src c=c'^(r&3)
  const int rS = t >> 2;
  const int cS = ((t & 3) ^ ((t >> 2) & 3)) * 8;
  const unsigned short* srcA = A + (size_t)(brow + rS) * K + cS;
  const unsigned short* srcB = B + (size_t)(bcol + rS) * K + cS;

#define STAGE_A(kt)                                                           \
  {                                                                           \
    const int s2 = ((kt) & 3) * 16384;                                        \
    const size_t ko = (size_t)(kt) * 32;                                      \
    GLOAD_LDS16(srcA + ko, &lds[s2 + t * 8]);                                 \
    GLOAD_LDS16(srcA + (size_t)128 * K + ko, &lds[s2 + 4096 + t * 8]);        \
  }
#define STAGE_B(kt)                                                           \
  {                                                                           \
    const int s2 = ((kt) & 3) * 16384;                                        \
    const size_t ko = (size_t)(kt) * 32;                                      \
    GLOAD_LDS16(srcB + ko, &lds[s2 + 8192 + t * 8]);                          \
    GLOAD_LDS16(srcB + (size_t)128 * K + ko, &lds[s2 + 12288 + t * 8]);       \
  }

  STAGE_A(0); STAGE_B(0);
  STAGE_A(1); STAGE_B(1);
  STAGE_A(2); STAGE_B(2);
  WAIT_VM8();
  FENCE(); BAR();

  f32x16 acc[4][2] = {};
  // fragment sh-indices (slot-relative), swizzled: r*32 + ((c ^ (r&3))*8),
  // c = 2*kh + hi.  r&3 == lane&3 for all our rows.
  int aIdx[4][2], bIdx[2][2];
#pragma unroll
  for (int m = 0; m < 4; ++m)
#pragma unroll
    for (int kh = 0; kh < 2; ++kh)
      aIdx[m][kh] = (wr * 128 + l31 + m * 32) * 32
                    + (((2 * kh + hi) ^ rx3) * 8);
#pragma unroll
  for (int n = 0; n < 2; ++n)
#pragma unroll
    for (int kh = 0; kh < 2; ++kh)
      bIdx[n][kh] = 8192 + (wc * 64 + l31 + n * 32) * 32
                    + (((2 * kh + hi) ^ rx3) * 8);

  for (int k = 0; k < NT; ++k) {
    const unsigned short* sl = &lds[(k & 3) * 16384];
    const bool pf = (k + 3 < NT);
    bf16x8 afr[2][2], bfr[2][2];

    // ---- phase A: m-tiles 0,1 ----
#pragma unroll
    for (int m = 0; m < 2; ++m)
#pragma unroll
      for (int kh = 0; kh < 2; ++kh)
        afr[m][kh] = *reinterpret_cast<const bf16x8*>(sl + aIdx[m][kh]);
#pragma unroll
    for (int n = 0; n < 2; ++n)
#pragma unroll
      for (int kh = 0; kh < 2; ++kh)
        bfr[n][kh] = *reinterpret_cast<const bf16x8*>(sl + bIdx[n][kh]);
    if (pf) STAGE_A(k + 3);
    FENCE(); BAR();
    WAIT_LGKM0(); SFENCE();
    __builtin_amdgcn_s_setprio(1);
#pragma unroll
    for (int m = 0; m < 2; ++m)
#pragma unroll
      for (int n = 0; n < 2; ++n)
#pragma unroll
        for (int kh = 0; kh < 2; ++kh)
          acc[m][n] = __builtin_amdgcn_mfma_f32_32x32x16_bf16(
              afr[m][kh], bfr[n][kh], acc[m][n], 0, 0, 0);
    __builtin_amdgcn_s_setprio(0);
    FENCE(); BAR();

    // ---- phase B: m-tiles 2,3 (B frags reused) ----
#pragma unroll
    for (int m = 0; m < 2; ++m)
#pragma unroll
      for (int kh = 0; kh < 2; ++kh)
        afr[m][kh] = *reinterpret_cast<const bf16x8*>(sl + aIdx[m + 2][kh]);
    if (pf) {
      STAGE_B(k + 3);
      WAIT_VM8();
    } else if (k == NT - 3) {
      WAIT_VM4();
    } else {
      WAIT_VM0();
    }
    FENCE(); BAR();
    WAIT_LGKM0(); SFENCE();
    __builtin_amdgcn_s_setprio(1);
#pragma unroll
    for (int m = 0; m < 2; ++m)
#pragma unroll
      for (int n = 0; n < 2; ++n)
#pragma unroll
        for (int kh = 0; kh < 2; ++kh)
          acc[m + 2][n] = __builtin_amdgcn_mfma_f32_32x32x16_bf16(
              afr[m][kh], bfr[n][kh], acc[m + 2][n], 0, 0, 0);
    __builtin_amdgcn_s_setprio(0);
    FENCE(); BAR();
  }
#undef STAGE_A
#undef STAGE_B

  const int ocol = bcol + wc * 64 + l31;
  const int rowb = brow + wr * 128 + 4 * hi;
#pragma unroll
  for (int m = 0; m < 4; ++m)
#pragma unroll
    for (int n = 0; n < 2; ++n)
#pragma unroll
      for (int rq = 0; rq < 4; ++rq)
#pragma unroll
        for (int j = 0; j < 4; ++j)
          C[(size_t)(rowb + m * 32 + 8 * rq + j) * N + (ocol + n * 32)] =
              acc[m][n][rq * 4 + j];
}

// ------------------------------ launch -------------------------------------

extern "C" void kernel_launch(void* const* d_in, const int* in_sizes, int n_in,
                              void* d_out, int out_size, void* d_ws,
                              size_t ws_size, hipStream_t stream) {
  const float* x  = (const float*)d_in[0];
  const float* w1 = (const float*)d_in[1];
  const float* w2 = (const float*)d_in[2];
  const float* w3 = (const float*)d_in[3];
  float* out = (float*)d_out;

  const int DIM = 4096, HID = 8192;
  const int M = in_sizes[0] / DIM;  // 8192

  char* xq  = (char*)d_ws;                              // M*DIM    (32 MB)
  char* w1q = xq + (size_t)M * DIM;                     // HID*DIM  (32 MB)
  char* w3q = w1q + (size_t)HID * DIM;                  // HID*DIM  (32 MB)
  unsigned short* w2b = (unsigned short*)(w3q + (size_t)HID * DIM);  // 64 MB
  unsigned short* h = w2b + (size_t)DIM * HID;          // M*HID bf16 (128 MB)
  float* sx  = (float*)(h + (size_t)M * HID);           // M
  float* sw1 = sx + M;                                  // HID
  float* sw3 = sw1 + HID;                               // HID

  quant_rows_i8_kernel<<<HID, 256, 0, stream>>>(w1, w1q, sw1, DIM, 1e-6f);
  quant_rows_i8_kernel<<<HID, 256, 0, stream>>>(w3, w3q, sw3, DIM, 1e-6f);
  quant_rows_i8_kernel<<<M, 256, 0, stream>>>(x, xq, sx, DIM, 1e-30f);
  quant_rows_bf16_kernel<<<DIM, 256, 0, stream>>>(w2, w2b, HID);

  gemm_i8_swiglu_kernel<<<dim3(HID / 128, M / 256), 512, 0, stream>>>(
      xq, w1q, w3q, sx, sw1, sw3, h, M, HID, DIM);
  gemm_bf16_kernel<<<dim3(DIM / 256, M / 256), 512, 0, stream>>>(
      h, w2b, out, M, DIM, HID);
}

// Round 6
// 1396.312 us; speedup vs baseline: 6.4983x; 1.0839x over previous
//
#include <hip/hip_runtime.h>
#include <hip/hip_bf16.h>
#include <stdint.h>

// ---------------------------------------------------------------------------
// SwiGLU + int8 weight-quant emulation (VNNILinear), MI355X gfx950. Round 6:
//   Both GEMMs: one-barrier-per-K-tile pipelined loop, double register sets
//   (ds_reads of next phase overlap MFMA of current), counted lgkmcnt(6),
//   vmcnt(8) slot gate, 4-slot 128 KiB LDS ring, 3-tiles-ahead prefetch.
//   Fused GEMM1/3: mfma_i32_32x32x32_i8, BK=64 (64-B rows, c^=r&3 2-bit
//     chunk swizzle -> empirically conflict-free per R3; R5's 32-B rows +
//     1-bit swizzle left 5e7 conflicts).
//   GEMM2: mfma_f32_32x32x16_bf16, 256x256, BK=32 (rows already 64 B).
// ---------------------------------------------------------------------------

typedef short bf16x8 __attribute__((ext_vector_type(8)));
typedef float f32x4  __attribute__((ext_vector_type(4)));
typedef float f32x16 __attribute__((ext_vector_type(16)));
typedef int   i32x4  __attribute__((ext_vector_type(4)));
typedef int   i32x16 __attribute__((ext_vector_type(16)));

__device__ __forceinline__ unsigned short f2bf(float f) {
  unsigned u = __builtin_bit_cast(unsigned, f);
  u += 0x7FFFu + ((u >> 16) & 1u);   // RNE
  return (unsigned short)(u >> 16);
}

#define GLOAD_LDS16(gaddr, laddr)                                             \
  __builtin_amdgcn_global_load_lds(                                           \
      (const __attribute__((address_space(1))) void*)(gaddr),                 \
      (__attribute__((address_space(3))) void*)(laddr), 16, 0, 0)

#define FENCE()      asm volatile("" ::: "memory")
#define BAR()        __builtin_amdgcn_s_barrier()
#define WAIT_LGKM0() asm volatile("s_waitcnt lgkmcnt(0)" ::: "memory")
#define WAIT_LGKM6() asm volatile("s_waitcnt lgkmcnt(6)" ::: "memory")
#define WAIT_VM8()   asm volatile("s_waitcnt vmcnt(8)" ::: "memory")
#define WAIT_VM4()   asm volatile("s_waitcnt vmcnt(4)" ::: "memory")
#define WAIT_VM0()   asm volatile("s_waitcnt vmcnt(0)" ::: "memory")
#define SFENCE()     __builtin_amdgcn_sched_barrier(0)

// --------------------------- preprocessing --------------------------------

__global__ void quant_rows_i8_kernel(const float* __restrict__ w,
                                     char* __restrict__ q,
                                     float* __restrict__ scale, int cols,
                                     float clip) {
  const int row = blockIdx.x;
  const float* wr = w + (size_t)row * cols;
  char* qr = q + (size_t)row * cols;

  float m = 0.f;
  for (int c = threadIdx.x * 4; c < cols; c += blockDim.x * 4) {
    float4 v = *reinterpret_cast<const float4*>(wr + c);
    m = fmaxf(m, fmaxf(fmaxf(fabsf(v.x), fabsf(v.y)),
                       fmaxf(fabsf(v.z), fabsf(v.w))));
  }
#pragma unroll
  for (int off = 32; off; off >>= 1) m = fmaxf(m, __shfl_xor(m, off));
  __shared__ float smax[4];
  if ((threadIdx.x & 63) == 0) smax[threadIdx.x >> 6] = m;
  __syncthreads();
  m = fmaxf(fmaxf(smax[0], smax[1]), fmaxf(smax[2], smax[3]));

  const float s = fmaxf(m, clip) / 127.0f;
  if (threadIdx.x == 0) scale[row] = s;
  for (int c = threadIdx.x * 4; c < cols; c += blockDim.x * 4) {
    float4 v = *reinterpret_cast<const float4*>(wr + c);
    int b0 = (int)rintf(v.x / s), b1 = (int)rintf(v.y / s);
    int b2 = (int)rintf(v.z / s), b3 = (int)rintf(v.w / s);
    unsigned pk = (b0 & 0xff) | ((b1 & 0xff) << 8) | ((b2 & 0xff) << 16)
                  | ((b3 & 0xff) << 24);
    *reinterpret_cast<unsigned*>(qr + c) = pk;
  }
}

__global__ void quant_rows_bf16_kernel(const float* __restrict__ w,
                                       unsigned short* __restrict__ wq,
                                       int cols) {
  const int row = blockIdx.x;
  const float* wr = w + (size_t)row * cols;
  unsigned short* wqr = wq + (size_t)row * cols;

  float m = 0.f;
  for (int c = threadIdx.x * 4; c < cols; c += blockDim.x * 4) {
    float4 v = *reinterpret_cast<const float4*>(wr + c);
    m = fmaxf(m, fmaxf(fmaxf(fabsf(v.x), fabsf(v.y)),
                       fmaxf(fabsf(v.z), fabsf(v.w))));
  }
#pragma unroll
  for (int off = 32; off; off >>= 1) m = fmaxf(m, __shfl_xor(m, off));
  __shared__ float smax[4];
  if ((threadIdx.x & 63) == 0) smax[threadIdx.x >> 6] = m;
  __syncthreads();
  m = fmaxf(fmaxf(smax[0], smax[1]), fmaxf(smax[2], smax[3]));

  const float s = fmaxf(m, 1e-6f) / 127.0f;
  for (int c = threadIdx.x * 4; c < cols; c += blockDim.x * 4) {
    float4 v = *reinterpret_cast<const float4*>(wr + c);
    ushort4 o;
    o.x = f2bf(rintf(v.x / s) * s);
    o.y = f2bf(rintf(v.y / s) * s);
    o.z = f2bf(rintf(v.z / s) * s);
    o.w = f2bf(rintf(v.w / s) * s);
    *reinterpret_cast<ushort4*>(wqr + c) = o;
  }
}

// ------------------------------ GEMMs -------------------------------------

__device__ __forceinline__ void xcd_swizzle(int& bx, int& by, int gx, int gy) {
  int nwg = gx * gy;              // both grids are % 8 == 0
  int bid = by * gx + bx;
  int cpx = nwg >> 3;
  int s = (bid & 7) * cpx + (bid >> 3);
  by = s / gx;
  bx = s % gx;
}

// Fused int8 GEMM: H = silu((xq@w1q^T)*sx*sw1) * ((xq@w3q^T)*sx*sw3), bf16.
// Tile 256x128, BK=64, 8 waves (2M x 4N), wave tile 128 rows x 32 dual-cols.
// LDS slot (32 KiB): A 256x64B [0,16K), B1 128x64B [16K,24K), B3 [24K,32K).
// 64-B rows, 4 chunks of 16 B, stored chunk = c ^ (r&3) both-sides.
__global__ __launch_bounds__(512, 2)
void gemm_i8_swiglu_kernel(const char* __restrict__ Aq,
                           const char* __restrict__ B1q,
                           const char* __restrict__ B3q,
                           const float* __restrict__ sx,
                           const float* __restrict__ sw1,
                           const float* __restrict__ sw3,
                           unsigned short* __restrict__ H,
                           int M, int N, int K) {
  __shared__ alignas(1024) char lds[131072];   // 4 slots x 32 KiB

  int bx = blockIdx.x, by = blockIdx.y;
  xcd_swizzle(bx, by, gridDim.x, gridDim.y);
  const int brow = by * 256, bcol = bx * 128;

  const int t = threadIdx.x, lane = t & 63, w = t >> 6;
  const int wr = w >> 2, wc = w & 3;
  const int l31 = lane & 31, hi = lane >> 5;
  const int NT = K >> 6;   // BK=64

  // staging: thread t -> row rS = t>>2 (and +128 for A's 2nd load), dest
  // chunk t&3; source chunk = (t&3) ^ (rS&3)  ((rS+128)&3 == rS&3).
  const int rS = t >> 2;
  const int gcS = ((t & 3) ^ (rS & 3)) * 16;
  const char* srcA  = Aq  + (size_t)(brow + rS) * K + gcS;
  const char* srcB1 = B1q + (size_t)(bcol + rS) * K + gcS;
  const char* srcB3 = B3q + (size_t)(bcol + rS) * K + gcS;

#define STAGE_A(kt)                                                           \
  {                                                                           \
    const int s2 = ((kt) & 3) * 32768;                                        \
    const size_t ko = (size_t)(kt) * 64;                                      \
    GLOAD_LDS16(srcA + ko, lds + s2 + t * 16);                                \
    GLOAD_LDS16(srcA + (size_t)128 * K + ko, lds + s2 + 8192 + t * 16);       \
  }
#define STAGE_B(kt)                                                           \
  {                                                                           \
    const int s2 = ((kt) & 3) * 32768;                                        \
    const size_t ko = (size_t)(kt) * 64;                                      \
    GLOAD_LDS16(srcB1 + ko, lds + s2 + 16384 + t * 16);                       \
    GLOAD_LDS16(srcB3 + ko, lds + s2 + 24576 + t * 16);                       \
  }

  STAGE_A(0); STAGE_B(0);
  STAGE_A(1); STAGE_B(1);
  STAGE_A(2); STAGE_B(2);
  WAIT_VM8();          // tile 0 landed (8 newest = tiles 1,2)
  FENCE(); BAR();

  // fragment offsets, kh=0 (logical chunk q = 2*kh + hi, stored q ^ (r&3));
  // kh=1 offset = kh=0 offset ^ 32 (chunk index differs in bit 1).
  const int cx = l31 & 3;
  const int aoff  = (wr * 128 + l31) * 64 + ((hi ^ cx) * 16);
  const int boff1 = 16384 + (wc * 32 + l31) * 64 + ((hi ^ cx) * 16);
  const int boff3 = boff1 + 8192;

  i32x16 acc[4][2] = {};         // [m][B1|B3]
  i32x4 a0[4], b10, b30;         // set0: kh=0 frags
  i32x4 a1[4], b11, b31;         // set1: kh=1 frags

  // preload set0 = (tile 0, kh0)
#pragma unroll
  for (int m = 0; m < 4; ++m)
    a0[m] = *reinterpret_cast<const i32x4*>(lds + aoff + m * 2048);
  b10 = *reinterpret_cast<const i32x4*>(lds + boff1);
  b30 = *reinterpret_cast<const i32x4*>(lds + boff3);

  for (int k = 0; k < NT; ++k) {
    const char* sl = lds + (k & 3) * 32768;
    const bool pf = (k + 3 < NT);

    // ---- P1: issue set1 (k,kh1) || STAGE_A(k+3) || MFMA set0 ----
#pragma unroll
    for (int m = 0; m < 4; ++m)
      a1[m] = *reinterpret_cast<const i32x4*>(sl + (aoff ^ 32) + m * 2048);
    b11 = *reinterpret_cast<const i32x4*>(sl + (boff1 ^ 32));
    b31 = *reinterpret_cast<const i32x4*>(sl + (boff3 ^ 32));
    if (pf) STAGE_A(k + 3);
    WAIT_LGKM6();                // set0 complete; set1 (6 newest) in flight
    SFENCE();
    __builtin_amdgcn_s_setprio(1);
#pragma unroll
    for (int m = 0; m < 4; ++m) {
      acc[m][0] = __builtin_amdgcn_mfma_i32_32x32x32_i8(a0[m], b10,
                                                        acc[m][0], 0, 0, 0);
      acc[m][1] = __builtin_amdgcn_mfma_i32_32x32x32_i8(a0[m], b30,
                                                        acc[m][1], 0, 0, 0);
    }
    __builtin_amdgcn_s_setprio(0);

    // ---- P2: STAGE_B(k+3); gate slot k+1; drain own ds reads (WAR);
    //          barrier; issue set0 (k+1,kh0); MFMA set1 ----
    if (pf) {
      STAGE_B(k + 3);
      WAIT_VM8();                // slot k+1 DMA (own share) done
    } else if (k == NT - 3) {
      WAIT_VM4();
    } else {
      WAIT_VM0();
    }
    WAIT_LGKM0();                // set1 reads done BEFORE barrier (WAR-safe:
                                 // slot k's rewrite is issued after this BAR)
    FENCE(); BAR();
    if (k + 1 < NT) {
      const char* sn = lds + ((k + 1) & 3) * 32768;
#pragma unroll
      for (int m = 0; m < 4; ++m)
        a0[m] = *reinterpret_cast<const i32x4*>(sn + aoff + m * 2048);
      b10 = *reinterpret_cast<const i32x4*>(sn + boff1);
      b30 = *reinterpret_cast<const i32x4*>(sn + boff3);
    }
    SFENCE();
    __builtin_amdgcn_s_setprio(1);
#pragma unroll
    for (int m = 0; m < 4; ++m) {
      acc[m][0] = __builtin_amdgcn_mfma_i32_32x32x32_i8(a1[m], b11,
                                                        acc[m][0], 0, 0, 0);
      acc[m][1] = __builtin_amdgcn_mfma_i32_32x32x32_i8(a1[m], b31,
                                                        acc[m][1], 0, 0, 0);
    }
    __builtin_amdgcn_s_setprio(0);
  }
#undef STAGE_A
#undef STAGE_B

  // ---- epilogue: dequant + SwiGLU -> bf16 (verified R4/R5) ----
  const int ocol = bcol + wc * 32 + l31;
  const int rowb = brow + wr * 128 + 4 * hi;
  const float sw1c = sw1[ocol], sw3c = sw3[ocol];
#pragma unroll
  for (int m = 0; m < 4; ++m) {
#pragma unroll
    for (int rq = 0; rq < 4; ++rq) {
      const int r0 = rowb + m * 32 + 8 * rq;
      const f32x4 sx4 = *reinterpret_cast<const f32x4*>(sx + r0);
#pragma unroll
      for (int j = 0; j < 4; ++j) {
        float y1 = (float)acc[m][0][rq * 4 + j] * (sx4[j] * sw1c);
        float y3 = (float)acc[m][1][rq * 4 + j] * (sx4[j] * sw3c);
        float hv = (y1 / (1.f + __expf(-y1))) * y3;
        H[(size_t)(r0 + j) * N + ocol] = f2bf(hv);
      }
    }
  }
}

// bf16 GEMM: C = A @ B^T (fp32 out). Tile 256x256, BK=32, 32x32x16 MFMA,
// same one-barrier pipelined skeleton. Rows 64 B, chunk swizzle c^=(r&3).
__global__ __launch_bounds__(512, 2)
void gemm_bf16_kernel(const unsigned short* __restrict__ A,
                      const unsigned short* __restrict__ B,
                      float* __restrict__ C, int M, int N, int K) {
  __shared__ alignas(1024) unsigned short lds[65536];  // 4 slots x 32 KiB

  int bx = blockIdx.x, by = blockIdx.y;
  xcd_swizzle(bx, by, gridDim.x, gridDim.y);
  const int brow = by * 256, bcol = bx * 256;

  const int t = threadIdx.x, lane = t & 63, w = t >> 6;
  const int wr = w >> 2, wc = w & 3;
  const int l31 = lane & 31, hi = lane >> 5;
  const int NT = K >> 5;   // BK=32

  const int rS = t >> 2;
  const int cS = ((t & 3) ^ (rS & 3)) * 8;   // sh units (16 B chunks)
  const unsigned short* srcA = A + (size_t)(brow + rS) * K + cS;
  const unsigned short* srcB = B + (size_t)(bcol + rS) * K + cS;

#define STAGE_A(kt)                                                           \
  {                                                                           \
    const int s2 = ((kt) & 3) * 16384;                                        \
    const size_t ko = (size_t)(kt) * 32;                                      \
    GLOAD_LDS16(srcA + ko, &lds[s2 + t * 8]);                                 \
    GLOAD_LDS16(srcA + (size_t)128 * K + ko, &lds[s2 + 4096 + t * 8]);        \
  }
#define STAGE_B(kt)                                                           \
  {                                                                           \
    const int s2 = ((kt) & 3) * 16384;                                        \
    const size_t ko = (size_t)(kt) * 32;                                      \
    GLOAD_LDS16(srcB + ko, &lds[s2 + 8192 + t * 8]);                          \
    GLOAD_LDS16(srcB + (size_t)128 * K + ko, &lds[s2 + 12288 + t * 8]);       \
  }

  STAGE_A(0); STAGE_B(0);
  STAGE_A(1); STAGE_B(1);
  STAGE_A(2); STAGE_B(2);
  WAIT_VM8();
  FENCE(); BAR();

  // kh=0 offsets in sh units; kh=1 = ^16 (chunk c^2 -> 2 chunks * 8 sh).
  const int cx = l31 & 3;
  const int aoff  = (wr * 128 + l31) * 32 + ((hi ^ cx) * 8);
  const int boff0 = 8192 + (wc * 64 + l31) * 32 + ((hi ^ cx) * 8);

  f32x16 acc[4][2] = {};
  bf16x8 a0[4], b00, b01;    // set0: kh=0 (b0n = B frag n)
  bf16x8 a1[4], b10, b11;    // set1: kh=1

#pragma unroll
  for (int m = 0; m < 4; ++m)
    a0[m] = *reinterpret_cast<const bf16x8*>(&lds[aoff + m * 1024]);
  b00 = *reinterpret_cast<const bf16x8*>(&lds[boff0]);
  b01 = *reinterpret_cast<const bf16x8*>(&lds[boff0 + 1024]);

  for (int k = 0; k < NT; ++k) {
    const unsigned short* sl = &lds[(k & 3) * 16384];
    const bool pf = (k + 3 < NT);

    // ---- P1 ----
#pragma unroll
    for (int m = 0; m < 4; ++m)
      a1[m] = *reinterpret_cast<const bf16x8*>(sl + (aoff ^ 16) + m * 1024);
    b10 = *reinterpret_cast<const bf16x8*>(sl + (boff0 ^ 16));
    b11 = *reinterpret_cast<const bf16x8*>(sl + ((boff0 + 1024) ^ 16));
    if (pf) STAGE_A(k + 3);
    WAIT_LGKM6();
    SFENCE();
    __builtin_amdgcn_s_setprio(1);
#pragma unroll
    for (int m = 0; m < 4; ++m) {
      acc[m][0] = __builtin_amdgcn_mfma_f32_32x32x16_bf16(a0[m], b00,
                                                          acc[m][0], 0, 0, 0);
      acc[m][1] = __builtin_amdgcn_mfma_f32_32x32x16_bf16(a0[m], b01,
                                                          acc[m][1], 0, 0, 0);
    }
    __builtin_amdgcn_s_setprio(0);

    // ---- P2 ----
    if (pf) {
      STAGE_B(k + 3);
      WAIT_VM8();
    } else if (k == NT - 3) {
      WAIT_VM4();
    } else {
      WAIT_VM0();
    }
    WAIT_LGKM0();
    FENCE(); BAR();
    if (k + 1 < NT) {
      const unsigned short* sn = &lds[((k + 1) & 3) * 16384];
#pragma unroll
      for (int m = 0; m < 4; ++m)
        a0[m] = *reinterpret_cast<const bf16x8*>(sn + aoff + m * 1024);
      b00 = *reinterpret_cast<const bf16x8*>(sn + boff0);
      b01 = *reinterpret_cast<const bf16x8*>(sn + boff0 + 1024);
    }
    SFENCE();
    __builtin_amdgcn_s_setprio(1);
#pragma unroll
    for (int m = 0; m < 4; ++m) {
      acc[m][0] = __builtin_amdgcn_mfma_f32_32x32x16_bf16(a1[m], b10,
                                                          acc[m][0], 0, 0, 0);
      acc[m][1] = __builtin_amdgcn_mfma_f32_32x32x16_bf16(a1[m], b11,
                                                          acc[m][1], 0, 0, 0);
    }
    __builtin_amdgcn_s_setprio(0);
  }
#undef STAGE_A
#undef STAGE_B

  const int ocol = bcol + wc * 64 + l31;
  const int rowb = brow + wr * 128 + 4 * hi;
#pragma unroll
  for (int m = 0; m < 4; ++m)
#pragma unroll
    for (int n = 0; n < 2; ++n)
#pragma unroll
      for (int rq = 0; rq < 4; ++rq)
#pragma unroll
        for (int j = 0; j < 4; ++j)
          C[(size_t)(rowb + m * 32 + 8 * rq + j) * N + (ocol + n * 32)] =
              acc[m][n][rq * 4 + j];
}

// ------------------------------ launch -------------------------------------

extern "C" void kernel_launch(void* const* d_in, const int* in_sizes, int n_in,
                              void* d_out, int out_size, void* d_ws,
                              size_t ws_size, hipStream_t stream) {
  const float* x  = (const float*)d_in[0];
  const float* w1 = (const float*)d_in[1];
  const float* w2 = (const float*)d_in[2];
  const float* w3 = (const float*)d_in[3];
  float* out = (float*)d_out;

  const int DIM = 4096, HID = 8192;
  const int M = in_sizes[0] / DIM;  // 8192

  char* xq  = (char*)d_ws;                              // M*DIM    (32 MB)
  char* w1q = xq + (size_t)M * DIM;                     // HID*DIM  (32 MB)
  char* w3q = w1q + (size_t)HID * DIM;                  // HID*DIM  (32 MB)
  unsigned short* w2b = (unsigned short*)(w3q + (size_t)HID * DIM);  // 64 MB
  unsigned short* h = w2b + (size_t)DIM * HID;          // M*HID bf16 (128 MB)
  float* sx  = (float*)(h + (size_t)M * HID);           // M
  float* sw1 = sx + M;                                  // HID
  float* sw3 = sw1 + HID;                               // HID

  quant_rows_i8_kernel<<<HID, 256, 0, stream>>>(w1, w1q, sw1, DIM, 1e-6f);
  quant_rows_i8_kernel<<<HID, 256, 0, stream>>>(w3, w3q, sw3, DIM, 1e-6f);
  quant_rows_i8_kernel<<<M, 256, 0, stream>>>(x, xq, sx, DIM, 1e-30f);
  quant_rows_bf16_kernel<<<DIM, 256, 0, stream>>>(w2, w2b, HID);

  gemm_i8_swiglu_kernel<<<dim3(HID / 128, M / 256), 512, 0, stream>>>(
      xq, w1q, w3q, sx, sw1, sw3, h, M, HID, DIM);
  gemm_bf16_kernel<<<dim3(DIM / 256, M / 256), 512, 0, stream>>>(
      h, w2b, out, M, DIM, HID);
}

// Round 7
// 1243.903 us; speedup vs baseline: 7.2945x; 1.1225x over previous
//
#include <hip/hip_runtime.h>
#include <hip/hip_bf16.h>
#include <stdint.h>

// ---------------------------------------------------------------------------
// SwiGLU + int8 weight-quant emulation (VNNILinear), MI355X gfx950. Round 7:
//   R6 pipeline kept (one-barrier-per-K-tile, double reg sets, counted
//   lgkmcnt/vmcnt, 4-slot ring, 3-ahead prefetch). ONLY change: LDS chunk
//   swizzle q ^ ((r>>1)&3)  [R3-verified zero-conflict pattern; R6's
//   q ^ (r&3) aliased with row-parity bank bit -> 1.5e8 conflict cycles].
// ---------------------------------------------------------------------------

typedef short bf16x8 __attribute__((ext_vector_type(8)));
typedef float f32x4  __attribute__((ext_vector_type(4)));
typedef float f32x16 __attribute__((ext_vector_type(16)));
typedef int   i32x4  __attribute__((ext_vector_type(4)));
typedef int   i32x16 __attribute__((ext_vector_type(16)));

__device__ __forceinline__ unsigned short f2bf(float f) {
  unsigned u = __builtin_bit_cast(unsigned, f);
  u += 0x7FFFu + ((u >> 16) & 1u);   // RNE
  return (unsigned short)(u >> 16);
}

#define GLOAD_LDS16(gaddr, laddr)                                             \
  __builtin_amdgcn_global_load_lds(                                           \
      (const __attribute__((address_space(1))) void*)(gaddr),                 \
      (__attribute__((address_space(3))) void*)(laddr), 16, 0, 0)

#define FENCE()      asm volatile("" ::: "memory")
#define BAR()        __builtin_amdgcn_s_barrier()
#define WAIT_LGKM0() asm volatile("s_waitcnt lgkmcnt(0)" ::: "memory")
#define WAIT_LGKM6() asm volatile("s_waitcnt lgkmcnt(6)" ::: "memory")
#define WAIT_VM8()   asm volatile("s_waitcnt vmcnt(8)" ::: "memory")
#define WAIT_VM4()   asm volatile("s_waitcnt vmcnt(4)" ::: "memory")
#define WAIT_VM0()   asm volatile("s_waitcnt vmcnt(0)" ::: "memory")
#define SFENCE()     __builtin_amdgcn_sched_barrier(0)

// --------------------------- preprocessing --------------------------------

__global__ void quant_rows_i8_kernel(const float* __restrict__ w,
                                     char* __restrict__ q,
                                     float* __restrict__ scale, int cols,
                                     float clip) {
  const int row = blockIdx.x;
  const float* wr = w + (size_t)row * cols;
  char* qr = q + (size_t)row * cols;

  float m = 0.f;
  for (int c = threadIdx.x * 4; c < cols; c += blockDim.x * 4) {
    float4 v = *reinterpret_cast<const float4*>(wr + c);
    m = fmaxf(m, fmaxf(fmaxf(fabsf(v.x), fabsf(v.y)),
                       fmaxf(fabsf(v.z), fabsf(v.w))));
  }
#pragma unroll
  for (int off = 32; off; off >>= 1) m = fmaxf(m, __shfl_xor(m, off));
  __shared__ float smax[4];
  if ((threadIdx.x & 63) == 0) smax[threadIdx.x >> 6] = m;
  __syncthreads();
  m = fmaxf(fmaxf(smax[0], smax[1]), fmaxf(smax[2], smax[3]));

  const float s = fmaxf(m, clip) / 127.0f;
  if (threadIdx.x == 0) scale[row] = s;
  for (int c = threadIdx.x * 4; c < cols; c += blockDim.x * 4) {
    float4 v = *reinterpret_cast<const float4*>(wr + c);
    int b0 = (int)rintf(v.x / s), b1 = (int)rintf(v.y / s);
    int b2 = (int)rintf(v.z / s), b3 = (int)rintf(v.w / s);
    unsigned pk = (b0 & 0xff) | ((b1 & 0xff) << 8) | ((b2 & 0xff) << 16)
                  | ((b3 & 0xff) << 24);
    *reinterpret_cast<unsigned*>(qr + c) = pk;
  }
}

__global__ void quant_rows_bf16_kernel(const float* __restrict__ w,
                                       unsigned short* __restrict__ wq,
                                       int cols) {
  const int row = blockIdx.x;
  const float* wr = w + (size_t)row * cols;
  unsigned short* wqr = wq + (size_t)row * cols;

  float m = 0.f;
  for (int c = threadIdx.x * 4; c < cols; c += blockDim.x * 4) {
    float4 v = *reinterpret_cast<const float4*>(wr + c);
    m = fmaxf(m, fmaxf(fmaxf(fabsf(v.x), fabsf(v.y)),
                       fmaxf(fabsf(v.z), fabsf(v.w))));
  }
#pragma unroll
  for (int off = 32; off; off >>= 1) m = fmaxf(m, __shfl_xor(m, off));
  __shared__ float smax[4];
  if ((threadIdx.x & 63) == 0) smax[threadIdx.x >> 6] = m;
  __syncthreads();
  m = fmaxf(fmaxf(smax[0], smax[1]), fmaxf(smax[2], smax[3]));

  const float s = fmaxf(m, 1e-6f) / 127.0f;
  for (int c = threadIdx.x * 4; c < cols; c += blockDim.x * 4) {
    float4 v = *reinterpret_cast<const float4*>(wr + c);
    ushort4 o;
    o.x = f2bf(rintf(v.x / s) * s);
    o.y = f2bf(rintf(v.y / s) * s);
    o.z = f2bf(rintf(v.z / s) * s);
    o.w = f2bf(rintf(v.w / s) * s);
    *reinterpret_cast<ushort4*>(wqr + c) = o;
  }
}

// ------------------------------ GEMMs -------------------------------------

__device__ __forceinline__ void xcd_swizzle(int& bx, int& by, int gx, int gy) {
  int nwg = gx * gy;              // both grids are % 8 == 0
  int bid = by * gx + bx;
  int cpx = nwg >> 3;
  int s = (bid & 7) * cpx + (bid >> 3);
  by = s / gx;
  bx = s % gx;
}

// Fused int8 GEMM: H = silu((xq@w1q^T)*sx*sw1) * ((xq@w3q^T)*sx*sw3), bf16.
// Tile 256x128, BK=64, 8 waves (2M x 4N), wave tile 128 rows x 32 dual-cols.
// LDS slot (32 KiB): A 256x64B [0,16K), B1 128x64B [16K,24K), B3 [24K,32K).
// 64-B rows, 4 chunks of 16 B; stored chunk = q ^ ((r>>1)&3)  [R3 pattern:
// 8 consecutive rows at one logical chunk hit all 32 banks].
__global__ __launch_bounds__(512, 2)
void gemm_i8_swiglu_kernel(const char* __restrict__ Aq,
                           const char* __restrict__ B1q,
                           const char* __restrict__ B3q,
                           const float* __restrict__ sx,
                           const float* __restrict__ sw1,
                           const float* __restrict__ sw3,
                           unsigned short* __restrict__ H,
                           int M, int N, int K) {
  __shared__ alignas(1024) char lds[131072];   // 4 slots x 32 KiB

  int bx = blockIdx.x, by = blockIdx.y;
  xcd_swizzle(bx, by, gridDim.x, gridDim.y);
  const int brow = by * 256, bcol = bx * 128;

  const int t = threadIdx.x, lane = t & 63, w = t >> 6;
  const int wr = w >> 2, wc = w & 3;
  const int l31 = lane & 31, hi = lane >> 5;
  const int NT = K >> 6;   // BK=64

  // staging: thread t -> row rS = t>>2, dest chunk p = t&3; source logical
  // chunk = p ^ ((rS>>1)&3) = (t&3) ^ ((t>>3)&3).  (rS+128 preserves rS>>1&3.)
  const int rS = t >> 2;
  const int gcS = ((t & 3) ^ ((t >> 3) & 3)) * 16;
  const char* srcA  = Aq  + (size_t)(brow + rS) * K + gcS;
  const char* srcB1 = B1q + (size_t)(bcol + rS) * K + gcS;
  const char* srcB3 = B3q + (size_t)(bcol + rS) * K + gcS;

#define STAGE_A(kt)                                                           \
  {                                                                           \
    const int s2 = ((kt) & 3) * 32768;                                        \
    const size_t ko = (size_t)(kt) * 64;                                      \
    GLOAD_LDS16(srcA + ko, lds + s2 + t * 16);                                \
    GLOAD_LDS16(srcA + (size_t)128 * K + ko, lds + s2 + 8192 + t * 16);       \
  }
#define STAGE_B(kt)                                                           \
  {                                                                           \
    const int s2 = ((kt) & 3) * 32768;                                        \
    const size_t ko = (size_t)(kt) * 64;                                      \
    GLOAD_LDS16(srcB1 + ko, lds + s2 + 16384 + t * 16);                       \
    GLOAD_LDS16(srcB3 + ko, lds + s2 + 24576 + t * 16);                       \
  }

  STAGE_A(0); STAGE_B(0);
  STAGE_A(1); STAGE_B(1);
  STAGE_A(2); STAGE_B(2);
  WAIT_VM8();          // tile 0 landed (8 newest = tiles 1,2)
  FENCE(); BAR();

  // fragment offsets, kh=0: logical chunk q = 2*kh + hi at stored position
  // q ^ ((r>>1)&3); kh=1 = kh=0 offset ^ 32 (chunk bit 1 <-> byte bit 5).
  const int sx2 = (l31 >> 1) & 3;
  const int aoff  = (wr * 128 + l31) * 64 + ((hi ^ sx2) * 16);
  const int boff1 = 16384 + (wc * 32 + l31) * 64 + ((hi ^ sx2) * 16);
  const int boff3 = boff1 + 8192;

  i32x16 acc[4][2] = {};         // [m][B1|B3]
  i32x4 a0[4], b10, b30;         // set0: kh=0 frags
  i32x4 a1[4], b11, b31;         // set1: kh=1 frags

  // preload set0 = (tile 0, kh0)
#pragma unroll
  for (int m = 0; m < 4; ++m)
    a0[m] = *reinterpret_cast<const i32x4*>(lds + aoff + m * 2048);
  b10 = *reinterpret_cast<const i32x4*>(lds + boff1);
  b30 = *reinterpret_cast<const i32x4*>(lds + boff3);

  for (int k = 0; k < NT; ++k) {
    const char* sl = lds + (k & 3) * 32768;
    const bool pf = (k + 3 < NT);

    // ---- P1: issue set1 (k,kh1) || STAGE_A(k+3) || MFMA set0 ----
#pragma unroll
    for (int m = 0; m < 4; ++m)
      a1[m] = *reinterpret_cast<const i32x4*>(sl + (aoff ^ 32) + m * 2048);
    b11 = *reinterpret_cast<const i32x4*>(sl + (boff1 ^ 32));
    b31 = *reinterpret_cast<const i32x4*>(sl + (boff3 ^ 32));
    if (pf) STAGE_A(k + 3);
    WAIT_LGKM6();                // set0 complete; set1 (6 newest) in flight
    SFENCE();
    __builtin_amdgcn_s_setprio(1);
#pragma unroll
    for (int m = 0; m < 4; ++m) {
      acc[m][0] = __builtin_amdgcn_mfma_i32_32x32x32_i8(a0[m], b10,
                                                        acc[m][0], 0, 0, 0);
      acc[m][1] = __builtin_amdgcn_mfma_i32_32x32x32_i8(a0[m], b30,
                                                        acc[m][1], 0, 0, 0);
    }
    __builtin_amdgcn_s_setprio(0);

    // ---- P2: STAGE_B(k+3); gate slot k+1; drain own ds reads (WAR);
    //          barrier; issue set0 (k+1,kh0); MFMA set1 ----
    if (pf) {
      STAGE_B(k + 3);
      WAIT_VM8();                // slot k+1 DMA (own share) done
    } else if (k == NT - 3) {
      WAIT_VM4();
    } else {
      WAIT_VM0();
    }
    WAIT_LGKM0();                // set1 reads done BEFORE barrier (WAR-safe)
    FENCE(); BAR();
    if (k + 1 < NT) {
      const char* sn = lds + ((k + 1) & 3) * 32768;
#pragma unroll
      for (int m = 0; m < 4; ++m)
        a0[m] = *reinterpret_cast<const i32x4*>(sn + aoff + m * 2048);
      b10 = *reinterpret_cast<const i32x4*>(sn + boff1);
      b30 = *reinterpret_cast<const i32x4*>(sn + boff3);
    }
    SFENCE();
    __builtin_amdgcn_s_setprio(1);
#pragma unroll
    for (int m = 0; m < 4; ++m) {
      acc[m][0] = __builtin_amdgcn_mfma_i32_32x32x32_i8(a1[m], b11,
                                                        acc[m][0], 0, 0, 0);
      acc[m][1] = __builtin_amdgcn_mfma_i32_32x32x32_i8(a1[m], b31,
                                                        acc[m][1], 0, 0, 0);
    }
    __builtin_amdgcn_s_setprio(0);
  }
#undef STAGE_A
#undef STAGE_B

  // ---- epilogue: dequant + SwiGLU -> bf16 (verified R4-R6) ----
  const int ocol = bcol + wc * 32 + l31;
  const int rowb = brow + wr * 128 + 4 * hi;
  const float sw1c = sw1[ocol], sw3c = sw3[ocol];
#pragma unroll
  for (int m = 0; m < 4; ++m) {
#pragma unroll
    for (int rq = 0; rq < 4; ++rq) {
      const int r0 = rowb + m * 32 + 8 * rq;
      const f32x4 sx4 = *reinterpret_cast<const f32x4*>(sx + r0);
#pragma unroll
      for (int j = 0; j < 4; ++j) {
        float y1 = (float)acc[m][0][rq * 4 + j] * (sx4[j] * sw1c);
        float y3 = (float)acc[m][1][rq * 4 + j] * (sx4[j] * sw3c);
        float hv = (y1 / (1.f + __expf(-y1))) * y3;
        H[(size_t)(r0 + j) * N + ocol] = f2bf(hv);
      }
    }
  }
}

// bf16 GEMM: C = A @ B^T (fp32 out). Tile 256x256, BK=32, 32x32x16 MFMA,
// same pipelined skeleton. 64-B rows, stored chunk = q ^ ((r>>1)&3).
__global__ __launch_bounds__(512, 2)
void gemm_bf16_kernel(const unsigned short* __restrict__ A,
                      const unsigned short* __restrict__ B,
                      float* __restrict__ C, int M, int N, int K) {
  __shared__ alignas(1024) unsigned short lds[65536];  // 4 slots x 32 KiB

  int bx = blockIdx.x, by = blockIdx.y;
  xcd_swizzle(bx, by, gridDim.x, gridDim.y);
  const int brow = by * 256, bcol = bx * 256;

  const int t = threadIdx.x, lane = t & 63, w = t >> 6;
  const int wr = w >> 2, wc = w & 3;
  const int l31 = lane & 31, hi = lane >> 5;
  const int NT = K >> 5;   // BK=32

  const int rS = t >> 2;
  const int cS = ((t & 3) ^ ((t >> 3) & 3)) * 8;   // sh units (16 B chunks)
  const unsigned short* srcA = A + (size_t)(brow + rS) * K + cS;
  const unsigned short* srcB = B + (size_t)(bcol + rS) * K + cS;

#define STAGE_A(kt)                                                           \
  {                                                                           \
    const int s2 = ((kt) & 3) * 16384;                                        \
    const size_t ko = (size_t)(kt) * 32;                                      \
    GLOAD_LDS16(srcA + ko, &lds[s2 + t * 8]);                                 \
    GLOAD_LDS16(srcA + (size_t)128 * K + ko, &lds[s2 + 4096 + t * 8]);        \
  }
#define STAGE_B(kt)                                                           \
  {                                                                           \
    const int s2 = ((kt) & 3) * 16384;                                        \
    const size_t ko = (size_t)(kt) * 32;                                      \
    GLOAD_LDS16(srcB + ko, &lds[s2 + 8192 + t * 8]);                          \
    GLOAD_LDS16(srcB + (size_t)128 * K + ko, &lds[s2 + 12288 + t * 8]);       \
  }

  STAGE_A(0); STAGE_B(0);
  STAGE_A(1); STAGE_B(1);
  STAGE_A(2); STAGE_B(2);
  WAIT_VM8();
  FENCE(); BAR();

  // kh=0 offsets in sh units; kh=1 = ^16 sh (chunk bit 1 <-> sh bit 4).
  const int sx2 = (l31 >> 1) & 3;
  const int aoff  = (wr * 128 + l31) * 32 + ((hi ^ sx2) * 8);
  const int boff0 = 8192 + (wc * 64 + l31) * 32 + ((hi ^ sx2) * 8);

  f32x16 acc[4][2] = {};
  bf16x8 a0[4], b00, b01;    // set0: kh=0
  bf16x8 a1[4], b10, b11;    // set1: kh=1

#pragma unroll
  for (int m = 0; m < 4; ++m)
    a0[m] = *reinterpret_cast<const bf16x8*>(&lds[aoff + m * 1024]);
  b00 = *reinterpret_cast<const bf16x8*>(&lds[boff0]);
  b01 = *reinterpret_cast<const bf16x8*>(&lds[boff0 + 1024]);

  for (int k = 0; k < NT; ++k) {
    const unsigned short* sl = &lds[(k & 3) * 16384];
    const bool pf = (k + 3 < NT);

    // ---- P1 ----
#pragma unroll
    for (int m = 0; m < 4; ++m)
      a1[m] = *reinterpret_cast<const bf16x8*>(sl + (aoff ^ 16) + m * 1024);
    b10 = *reinterpret_cast<const bf16x8*>(sl + (boff0 ^ 16));
    b11 = *reinterpret_cast<const bf16x8*>(sl + ((boff0 + 1024) ^ 16));
    if (pf) STAGE_A(k + 3);
    WAIT_LGKM6();
    SFENCE();
    __builtin_amdgcn_s_setprio(1);
#pragma unroll
    for (int m = 0; m < 4; ++m) {
      acc[m][0] = __builtin_amdgcn_mfma_f32_32x32x16_bf16(a0[m], b00,
                                                          acc[m][0], 0, 0, 0);
      acc[m][1] = __builtin_amdgcn_mfma_f32_32x32x16_bf16(a0[m], b01,
                                                          acc[m][1], 0, 0, 0);
    }
    __builtin_amdgcn_s_setprio(0);

    // ---- P2 ----
    if (pf) {
      STAGE_B(k + 3);
      WAIT_VM8();
    } else if (k == NT - 3) {
      WAIT_VM4();
    } else {
      WAIT_VM0();
    }
    WAIT_LGKM0();
    FENCE(); BAR();
    if (k + 1 < NT) {
      const unsigned short* sn = &lds[((k + 1) & 3) * 16384];
#pragma unroll
      for (int m = 0; m < 4; ++m)
        a0[m] = *reinterpret_cast<const bf16x8*>(sn + aoff + m * 1024);
      b00 = *reinterpret_cast<const bf16x8*>(sn + boff0);
      b01 = *reinterpret_cast<const bf16x8*>(sn + boff0 + 1024);
    }
    SFENCE();
    __builtin_amdgcn_s_setprio(1);
#pragma unroll
    for (int m = 0; m < 4; ++m) {
      acc[m][0] = __builtin_amdgcn_mfma_f32_32x32x16_bf16(a1[m], b10,
                                                          acc[m][0], 0, 0, 0);
      acc[m][1] = __builtin_amdgcn_mfma_f32_32x32x16_bf16(a1[m], b11,
                                                          acc[m][1], 0, 0, 0);
    }
    __builtin_amdgcn_s_setprio(0);
  }
#undef STAGE_A
#undef STAGE_B

  const int ocol = bcol + wc * 64 + l31;
  const int rowb = brow + wr * 128 + 4 * hi;
#pragma unroll
  for (int m = 0; m < 4; ++m)
#pragma unroll
    for (int n = 0; n < 2; ++n)
#pragma unroll
      for (int rq = 0; rq < 4; ++rq)
#pragma unroll
        for (int j = 0; j < 4; ++j)
          C[(size_t)(rowb + m * 32 + 8 * rq + j) * N + (ocol + n * 32)] =
              acc[m][n][rq * 4 + j];
}

// ------------------------------ launch -------------------------------------

extern "C" void kernel_launch(void* const* d_in, const int* in_sizes, int n_in,
                              void* d_out, int out_size, void* d_ws,
                              size_t ws_size, hipStream_t stream) {
  const float* x  = (const float*)d_in[0];
  const float* w1 = (const float*)d_in[1];
  const float* w2 = (const float*)d_in[2];
  const float* w3 = (const float*)d_in[3];
  float* out = (float*)d_out;

  const int DIM = 4096, HID = 8192;
  const int M = in_sizes[0] / DIM;  // 8192

  char* xq  = (char*)d_ws;                              // M*DIM    (32 MB)
  char* w1q = xq + (size_t)M * DIM;                     // HID*DIM  (32 MB)
  char* w3q = w1q + (size_t)HID * DIM;                  // HID*DIM  (32 MB)
  unsigned short* w2b = (unsigned short*)(w3q + (size_t)HID * DIM);  // 64 MB
  unsigned short* h = w2b + (size_t)DIM * HID;          // M*HID bf16 (128 MB)
  float* sx  = (float*)(h + (size_t)M * HID);           // M
  float* sw1 = sx + M;                                  // HID
  float* sw3 = sw1 + HID;                               // HID

  quant_rows_i8_kernel<<<HID, 256, 0, stream>>>(w1, w1q, sw1, DIM, 1e-6f);
  quant_rows_i8_kernel<<<HID, 256, 0, stream>>>(w3, w3q, sw3, DIM, 1e-6f);
  quant_rows_i8_kernel<<<M, 256, 0, stream>>>(x, xq, sx, DIM, 1e-30f);
  quant_rows_bf16_kernel<<<DIM, 256, 0, stream>>>(w2, w2b, HID);

  gemm_i8_swiglu_kernel<<<dim3(HID / 128, M / 256), 512, 0, stream>>>(
      xq, w1q, w3q, sx, sw1, sw3, h, M, HID, DIM);
  gemm_bf16_kernel<<<dim3(DIM / 256, M / 256), 512, 0, stream>>>(
      h, w2b, out, M, DIM, HID);
}